// Round 6
// baseline (47.202 us; speedup 1.0000x reference)
//
#include <hip/hip_runtime.h>

// out[b, k] = in[b, TRI_I[k]] * in[b, TRI_J[k]], k over strictly-lower-tri
// (i>j) pairs of a 512x512 matrix, row-major (i,j) order.
// B=512, N=512, NC2 = 512*511/2 = 130816.

#define N_ATOMS 512
#define NC2     130816
#define NQ4     (NC2 / 4)   // 32704 float4 stores per batch row
#define GX      8           // blocks per batch (compile-time)
#define NITER   16          // 8*256*16 = 32768 >= 32704

// Skewed LDS index: bank = (t + t/32) % 32 — keeps the 4-stride lane
// pattern conflict-free (2-way, which is free on CDNA4).
__device__ __forceinline__ int skew(int t) { return t + (t >> 5); }

__global__ __launch_bounds__(256, 8)
void ncp_kernel(const float* __restrict__ in, float* __restrict__ out) {
    __shared__ float row[N_ATOMS + (N_ATOMS >> 5) + 8];   // 536 floats
    const int b   = blockIdx.y;
    const int tid = threadIdx.x;

    // Stage this batch's 512-float row into LDS at skewed indices.
    {
        const float2* src = reinterpret_cast<const float2*>(in + (size_t)b * N_ATOMS);
        float2 v = src[tid];
        const int t = 2 * tid;          // t even: skew(t)+1 == skew(t+1)
        row[skew(t)]     = v.x;
        row[skew(t) + 1] = v.y;
    }
    __syncthreads();

    float4* outb = reinterpret_cast<float4*>(out + (size_t)b * NC2);
    const int q0 = blockIdx.x * 256 + tid;

#pragma unroll 4
    for (int s = 0; s < NITER; ++s) {
        const int q = q0 + s * (GX * 256);
        if (q < NQ4) {
            const int k = q * 4;

            // i estimate: 8k+1 < 2^20 is exact in fp32, sqrtf correctly
            // rounded -> estimate off by at most 1 -> single-step fixup.
            int i  = (int)(0.5f * (1.0f + sqrtf(8.0f * (float)k + 1.0f)));
            int t2 = (i * (i - 1)) >> 1;
            if (t2 > k)           { t2 -= --i; }   // i too big
            else if (k >= t2 + i) { t2 += i++; }   // i too small
            int j = k - t2;

            float ri = row[skew(i)];
            float4 v;
            float* vp = &v.x;
#pragma unroll
            for (int t = 0; t < 4; ++t) {
                vp[t] = ri * row[skew(j)];
                ++j; bool c = (j == i); i += c; j = c ? 0 : j; ri = row[skew(i)];
            }
            outb[q] = v;
        }
    }
}

extern "C" void kernel_launch(void* const* d_in, const int* in_sizes, int n_in,
                              void* d_out, int out_size, void* d_ws, size_t ws_size,
                              hipStream_t stream) {
    const float* atom_nc = (const float*)d_in[0];
    float* out = (float*)d_out;

    dim3 grid(GX, 512);
    dim3 block(256);
    ncp_kernel<<<grid, block, 0, stream>>>(atom_nc, out);
}

// Round 7
// 46.218 us; speedup vs baseline: 1.0213x; 1.0213x over previous
//
#include <hip/hip_runtime.h>

// out[b, k] = in[b, TRI_I[k]] * in[b, TRI_J[k]], k over strictly-lower-tri
// (i>j) pairs of a 512x512 matrix, row-major (i,j) order.
// B=512, N=512, NC2 = 512*511/2 = 130816.

#define N_ATOMS 512
#define NC2     130816
#define NQ4     (NC2 / 4)    // 32704 float4 stores per batch row
#define BLK     1024         // one block per batch
#define NFULL   (NQ4 / BLK)  // 31 full iterations
#define NTAIL   (NQ4 - NFULL * BLK)  // 960

// Skewed LDS index: bank = (t + t/32) % 32 — keeps the 4-stride lane
// pattern conflict-free (2-way, which is free on CDNA4).
__device__ __forceinline__ int skew(int t) { return t + (t >> 5); }

__device__ __forceinline__ void do_quad(const float* __restrict__ row,
                                        float4* __restrict__ outb, int q) {
    const int k = q * 4;
    // i estimate: 8k+1 < 2^20 exact in fp32, sqrtf correctly rounded ->
    // off by at most 1 -> single-step fixup.
    int i  = (int)(0.5f * (1.0f + sqrtf(8.0f * (float)k + 1.0f)));
    int t2 = (i * (i - 1)) >> 1;
    if (t2 > k)           { t2 -= --i; }   // i too big
    else if (k >= t2 + i) { t2 += i++; }   // i too small
    int j = k - t2;

    float ri = row[skew(i)];
    float4 v;
    float* vp = &v.x;
#pragma unroll
    for (int t = 0; t < 4; ++t) {
        vp[t] = ri * row[skew(j)];
        ++j; bool c = (j == i); i += c; j = c ? 0 : j; ri = row[skew(i)];
    }
    outb[q] = v;
}

__global__ __launch_bounds__(BLK, 8)
void ncp_kernel(const float* __restrict__ in, float* __restrict__ out) {
    __shared__ float row[N_ATOMS + (N_ATOMS >> 5) + 8];
    const int b   = blockIdx.x;
    const int tid = threadIdx.x;

    // Stage this batch's 512-float row into LDS (threads 0..511).
    if (tid < N_ATOMS) {
        row[skew(tid)] = in[(size_t)b * N_ATOMS + tid];
    }
    __syncthreads();

    float4* outb = reinterpret_cast<float4*>(out + (size_t)b * NC2);

#pragma unroll 4
    for (int s = 0; s < NFULL; ++s) {
        do_quad(row, outb, s * BLK + tid);      // always in range
    }
    if (tid < NTAIL) {
        do_quad(row, outb, NFULL * BLK + tid);  // tail: 960 threads
    }
}

extern "C" void kernel_launch(void* const* d_in, const int* in_sizes, int n_in,
                              void* d_out, int out_size, void* d_ws, size_t ws_size,
                              hipStream_t stream) {
    const float* atom_nc = (const float*)d_in[0];
    float* out = (float*)d_out;

    dim3 grid(512);    // one block per batch
    dim3 block(BLK);
    ncp_kernel<<<grid, block, 0, stream>>>(atom_nc, out);
}